// Round 1
// baseline (1142.116 us; speedup 1.0000x reference)
//
#include <hip/hip_runtime.h>
#include <cstdint>

#define B_ 4096
#define F_ 1024
#define H_ 16384
#define TOPK 64
#define MAXC 192
#define NBINS 2048

typedef unsigned short u16;
typedef __attribute__((ext_vector_type(8))) short bf16x8;
typedef __attribute__((ext_vector_type(4))) float f32x4;

__device__ __forceinline__ u16 f2bf(float f) {
  union { float f; uint32_t u; } v; v.f = f;
  uint32_t u = v.u;
  uint32_t r = u + 0x7FFFu + ((u >> 16) & 1u);
  return (u16)(r >> 16);
}
__device__ __forceinline__ float bf2f(u16 h) {
  union { uint32_t u; float f; } v; v.u = ((uint32_t)h) << 16; return v.f;
}

__device__ __forceinline__ void async16(const void* g, void* l) {
  __builtin_amdgcn_global_load_lds(
      reinterpret_cast<const __attribute__((address_space(1))) uint32_t*>(
          reinterpret_cast<uintptr_t>(g)),
      reinterpret_cast<__attribute__((address_space(3))) uint32_t*>(
          reinterpret_cast<uintptr_t>(l)),
      16, 0, 0);
}

// ---- K0a: xbar = bf16(x - b_dec) ----
__global__ __launch_bounds__(256) void k_xbar(const float* __restrict__ x,
                                              const float* __restrict__ b_dec,
                                              u16* __restrict__ xbar) {
  int i = blockIdx.x * 256 + threadIdx.x;
  int base = i * 4;
  int col = base & (F_ - 1);
  float4 xv = *(const float4*)(x + base);
  float4 bv = *(const float4*)(b_dec + col);
  ushort4 o;
  o.x = f2bf(xv.x - bv.x); o.y = f2bf(xv.y - bv.y);
  o.z = f2bf(xv.z - bv.z); o.w = f2bf(xv.w - bv.w);
  *(ushort4*)(xbar + base) = o;
}

// ---- K0b: bf16 cast of W_enc ----
__global__ __launch_bounds__(256) void k_cast(const float* __restrict__ src,
                                              u16* __restrict__ dst) {
  size_t base = (size_t)(blockIdx.x * 256 + threadIdx.x) * 4;
  float4 v = *(const float4*)(src + base);
  ushort4 o; o.x = f2bf(v.x); o.y = f2bf(v.y); o.z = f2bf(v.z); o.w = f2bf(v.w);
  *(ushort4*)(dst + base) = o;
}

// ---- K0c: W_dec [F,H] fp32 -> W_decT [H,F] bf16 ----
__global__ __launch_bounds__(256) void k_transpose(const float* __restrict__ Wdec,
                                                   u16* __restrict__ WdecT) {
  __shared__ float tile[32][33];
  int hb = blockIdx.x * 32, fb = blockIdx.y * 32;
  int tx = threadIdx.x & 31, ty = threadIdx.x >> 5;  // ty 0..7
#pragma unroll
  for (int i = 0; i < 32; i += 8)
    tile[ty + i][tx] = Wdec[(size_t)(fb + ty + i) * H_ + hb + tx];
  __syncthreads();
#pragma unroll
  for (int i = 0; i < 32; i += 8)
    WdecT[(size_t)(hb + ty + i) * F_ + fb + tx] = f2bf(tile[tx][ty + i]);
}

// ---- K1: bf16 MFMA GEMM: a[b][h] = sum_k xbar[b][k]*Wenc[h][k] + b_enc[h] ----
// 128x128 tile, BK=32, 256 thr = 4 waves (2x2 of 64x64), 16x16x32 mfma.
__global__ __launch_bounds__(256) void k_gemm(const u16* __restrict__ A,
                                              const u16* __restrict__ Bm,
                                              const float* __restrict__ b_enc,
                                              float* __restrict__ C) {
  __shared__ u16 lA[128 * 32];
  __shared__ u16 lB[128 * 32];
  const int tid = threadIdx.x;
  const int lane = tid & 63, wave = tid >> 6;
  const int wm = wave >> 1, wn = wave & 1;
  const int bx = blockIdx.x, by = blockIdx.y;

  // staging: thread tid covers 16B at lds byte tid*16 (sweep0) and +4096 (sweep1)
  const u16* gA0 = A + (size_t)(by * 128 + (tid >> 2)) * F_ + (tid & 3) * 8;
  const u16* gB0 = Bm + (size_t)(bx * 128 + (tid >> 2)) * F_ + (tid & 3) * 8;
  u16* lA0 = &lA[tid * 8];
  u16* lB0 = &lB[tid * 8];

  f32x4 acc[4][4] = {};
  const int lm = lane & 15;
  const int kq = (lane >> 4) * 8;

  for (int k0 = 0; k0 < F_; k0 += 32) {
    async16(gA0 + k0, lA0);
    async16(gA0 + 64 * F_ + k0, lA0 + 2048);
    async16(gB0 + k0, lB0);
    async16(gB0 + 64 * F_ + k0, lB0 + 2048);
    __syncthreads();
    bf16x8 av[4], bv[4];
#pragma unroll
    for (int i = 0; i < 4; ++i)
      av[i] = *(const bf16x8*)&lA[(wm * 64 + i * 16 + lm) * 32 + kq];
#pragma unroll
    for (int j = 0; j < 4; ++j)
      bv[j] = *(const bf16x8*)&lB[(wn * 64 + j * 16 + lm) * 32 + kq];
#pragma unroll
    for (int i = 0; i < 4; ++i)
#pragma unroll
      for (int j = 0; j < 4; ++j)
        acc[i][j] = __builtin_amdgcn_mfma_f32_16x16x32_bf16(av[i], bv[j], acc[i][j], 0, 0, 0);
    __syncthreads();
  }

#pragma unroll
  for (int i = 0; i < 4; ++i) {
    int rowg = by * 128 + wm * 64 + i * 16 + (lane >> 4) * 4;
#pragma unroll
    for (int j = 0; j < 4; ++j) {
      int colg = bx * 128 + wn * 64 + j * 16 + lm;
      float be = b_enc[colg];
      float* cp = C + (size_t)rowg * H_ + colg;
#pragma unroll
      for (int r = 0; r < 4; ++r) cp[(size_t)r * H_] = acc[i][j][r] + be;
    }
  }
}

// ---- K2: per-row histogram select of candidates (margin below approx t64), zero row ----
__global__ __launch_bounds__(256) void k_select(float* __restrict__ a,
                                               int* __restrict__ candIdx,
                                               int* __restrict__ candCnt) {
  const int row = blockIdx.x, tid = threadIdx.x;
  float* arow = a + (size_t)row * H_;
  __shared__ int hist[NBINS];
  __shared__ float s_cut;
  __shared__ int s_cnt;
  for (int i = tid; i < NBINS; i += 256) hist[i] = 0;
  if (tid == 0) s_cnt = 0;
  __syncthreads();
  for (int h = tid; h < H_; h += 256) {
    float v = arow[h];
    int b = (int)floorf((v + 4.0f) * 256.0f);
    b = b < 0 ? 0 : (b > NBINS - 1 ? NBINS - 1 : b);
    atomicAdd(&hist[b], 1);
  }
  __syncthreads();
  if (tid == 0) {
    int c = 0, i = NBINS - 1;
    for (; i > 0; --i) { c += hist[i]; if (c >= TOPK) break; }
    s_cut = ((float)i * (1.0f / 256.0f) - 4.0f) - 0.025f;  // bin edge minus margin
  }
  __syncthreads();
  const float cut = s_cut;
  for (int h = tid; h < H_; h += 256) {
    float v = arow[h];
    if (v >= cut) {
      int p = atomicAdd(&s_cnt, 1);
      if (p < MAXC) candIdx[row * MAXC + p] = h;
    }
    arow[h] = 0.0f;  // same thread read-then-zero: safe
  }
  __syncthreads();
  if (tid == 0) candCnt[row] = s_cnt < MAXC ? s_cnt : MAXC;
}

// ---- K3: fp64 refinement of candidates, exact top-64, scatter + compact list ----
__global__ __launch_bounds__(256) void k_refine(const float* __restrict__ x,
                                               const float* __restrict__ b_dec,
                                               const float* __restrict__ Wenc,
                                               const float* __restrict__ b_enc,
                                               const int* __restrict__ candIdx,
                                               const int* __restrict__ candCnt,
                                               float* __restrict__ f,
                                               int* __restrict__ decIdx,
                                               float* __restrict__ decVal) {
  const int row = blockIdx.x, tid = threadIdx.x;
  const int lane = tid & 63, wave = tid >> 6;
  __shared__ double xl[F_];
  __shared__ double vals[MAXC];
  __shared__ int idxs[MAXC];
  for (int k = tid; k < F_; k += 256)
    xl[k] = (double)x[(size_t)row * F_ + k] - (double)b_dec[k];
  const int cnt = candCnt[row];
  for (int c = tid; c < cnt; c += 256) idxs[c] = candIdx[row * MAXC + c];
  __syncthreads();
  for (int c = wave; c < cnt; c += 4) {
    const int h = idxs[c];
    const float* wr = Wenc + (size_t)h * F_;
    double s = 0.0;
    for (int k = lane; k < F_; k += 64) s += xl[k] * (double)wr[k];
#pragma unroll
    for (int off = 32; off > 0; off >>= 1) s += __shfl_down(s, off);
    if (lane == 0) vals[c] = s + (double)b_enc[h];
  }
  __syncthreads();
  for (int c = tid; c < cnt; c += 256) {
    const double v = vals[c];
    const int h = idxs[c];
    int rank = 0;
    for (int o = 0; o < cnt; ++o) {
      double vo = vals[o];
      rank += (vo > v) || (vo == v && idxs[o] < h);  // jax tie-break: lower idx first
    }
    if (rank < TOPK) {
      float fv = v > 0.0 ? (float)v : 0.0f;
      f[(size_t)row * H_ + h] = fv;
      decIdx[row * TOPK + rank] = h;
      decVal[row * TOPK + rank] = fv;
    }
  }
}

// ---- K4: sparse decode: xhat[b,:] = sum_j val_j * W_decT[idx_j,:] + b_dec ----
__global__ __launch_bounds__(256) void k_decode(const int* __restrict__ decIdx,
                                               const float* __restrict__ decVal,
                                               const u16* __restrict__ WdecT,
                                               const float* __restrict__ b_dec,
                                               float* __restrict__ xhat) {
  const int row = blockIdx.x, tid = threadIdx.x;
  __shared__ int sIdx[TOPK];
  __shared__ float sVal[TOPK];
  if (tid < TOPK) {
    sIdx[tid] = decIdx[row * TOPK + tid];
    sVal[tid] = decVal[row * TOPK + tid];
  }
  __syncthreads();
  const int fb = tid * 4;
  float4 bd = *(const float4*)(b_dec + fb);
  float a0 = bd.x, a1 = bd.y, a2 = bd.z, a3 = bd.w;
#pragma unroll 4
  for (int j = 0; j < TOPK; ++j) {
    const float v = sVal[j];
    const ushort4 w = *(const ushort4*)(WdecT + (size_t)sIdx[j] * F_ + fb);
    a0 += v * bf2f(w.x); a1 += v * bf2f(w.y);
    a2 += v * bf2f(w.z); a3 += v * bf2f(w.w);
  }
  float4 o; o.x = a0; o.y = a1; o.z = a2; o.w = a3;
  *(float4*)(xhat + (size_t)row * F_ + fb) = o;
}

extern "C" void kernel_launch(void* const* d_in, const int* in_sizes, int n_in,
                              void* d_out, int out_size, void* d_ws, size_t ws_size,
                              hipStream_t stream) {
  const float* x    = (const float*)d_in[0];
  const float* Wenc = (const float*)d_in[1];
  const float* benc = (const float*)d_in[2];
  const float* Wdec = (const float*)d_in[3];
  const float* bdec = (const float*)d_in[4];
  // d_in[5] = activate (k=64), hardcoded

  float* out  = (float*)d_out;
  float* f    = out;                       // [4096][16384]
  float* xhat = out + (size_t)B_ * H_;     // [4096][1024]

  char* ws = (char*)d_ws;
  u16*  xbar    = (u16*)ws;                          // 8 MB
  u16*  wencb   = (u16*)(ws + (size_t)(8)  * 1048576);  // 32 MB
  u16*  wdecT   = (u16*)(ws + (size_t)(40) * 1048576);  // 32 MB
  int*  candIdx = (int*)(ws + (size_t)(72) * 1048576);  // 3 MB
  int*  candCnt = (int*)(ws + (size_t)(75) * 1048576);  // 16 KB
  int*  decIdx  = (int*)(ws + (size_t)(76) * 1048576);  // 1 MB
  float* decVal = (float*)(ws + (size_t)(77) * 1048576);// 1 MB  (total 78 MB)

  k_xbar<<<B_ * F_ / 1024, 256, 0, stream>>>(x, bdec, xbar);
  k_cast<<<H_ * F_ / 1024, 256, 0, stream>>>(Wenc, wencb);
  k_transpose<<<dim3(H_ / 32, F_ / 32), 256, 0, stream>>>(Wdec, wdecT);
  k_gemm<<<dim3(H_ / 128, B_ / 128), 256, 0, stream>>>(xbar, wencb, benc, f);
  k_select<<<B_, 256, 0, stream>>>(f, candIdx, candCnt);
  k_refine<<<B_, 256, 0, stream>>>(x, bdec, Wenc, benc, candIdx, candCnt, f, decIdx, decVal);
  k_decode<<<B_, 256, 0, stream>>>(decIdx, decVal, wdecT, bdec, xhat);
}

// Round 2
// 1008.510 us; speedup vs baseline: 1.1325x; 1.1325x over previous
//
#include <hip/hip_runtime.h>
#include <cstdint>

#define B_ 4096
#define F_ 1024
#define H_ 16384
#define TOPK 64
#define MAXC 192
#define NBINS 2048

typedef unsigned short u16;
typedef __attribute__((ext_vector_type(8))) short bf16x8;
typedef __attribute__((ext_vector_type(4))) float f32x4;

__device__ __forceinline__ u16 f2bf(float f) {
  union { float f; uint32_t u; } v; v.f = f;
  uint32_t u = v.u;
  uint32_t r = u + 0x7FFFu + ((u >> 16) & 1u);
  return (u16)(r >> 16);
}
__device__ __forceinline__ float bf2f(u16 h) {
  union { uint32_t u; float f; } v; v.u = ((uint32_t)h) << 16; return v.f;
}

__device__ __forceinline__ void async16(const void* g, void* l) {
  __builtin_amdgcn_global_load_lds(
      reinterpret_cast<const __attribute__((address_space(1))) uint32_t*>(
          reinterpret_cast<uintptr_t>(g)),
      reinterpret_cast<__attribute__((address_space(3))) uint32_t*>(
          reinterpret_cast<uintptr_t>(l)),
      16, 0, 0);
}

// ---- K0a: xbar = bf16(x - b_dec) ----
__global__ __launch_bounds__(256) void k_xbar(const float* __restrict__ x,
                                              const float* __restrict__ b_dec,
                                              u16* __restrict__ xbar) {
  int i = blockIdx.x * 256 + threadIdx.x;
  int base = i * 4;
  int col = base & (F_ - 1);
  float4 xv = *(const float4*)(x + base);
  float4 bv = *(const float4*)(b_dec + col);
  ushort4 o;
  o.x = f2bf(xv.x - bv.x); o.y = f2bf(xv.y - bv.y);
  o.z = f2bf(xv.z - bv.z); o.w = f2bf(xv.w - bv.w);
  *(ushort4*)(xbar + base) = o;
}

// ---- K0b: bf16 cast of W_enc ----
__global__ __launch_bounds__(256) void k_cast(const float* __restrict__ src,
                                              u16* __restrict__ dst) {
  size_t base = (size_t)(blockIdx.x * 256 + threadIdx.x) * 4;
  float4 v = *(const float4*)(src + base);
  ushort4 o; o.x = f2bf(v.x); o.y = f2bf(v.y); o.z = f2bf(v.z); o.w = f2bf(v.w);
  *(ushort4*)(dst + base) = o;
}

// ---- K0c: W_dec [F,H] fp32 -> W_decT [H,F] bf16 ----
__global__ __launch_bounds__(256) void k_transpose(const float* __restrict__ Wdec,
                                                   u16* __restrict__ WdecT) {
  __shared__ float tile[32][33];
  int hb = blockIdx.x * 32, fb = blockIdx.y * 32;
  int tx = threadIdx.x & 31, ty = threadIdx.x >> 5;  // ty 0..7
#pragma unroll
  for (int i = 0; i < 32; i += 8)
    tile[ty + i][tx] = Wdec[(size_t)(fb + ty + i) * H_ + hb + tx];
  __syncthreads();
#pragma unroll
  for (int i = 0; i < 32; i += 8)
    WdecT[(size_t)(hb + ty + i) * F_ + fb + tx] = f2bf(tile[tx][ty + i]);
}

// ---- K1: bf16 MFMA GEMM: a[b][h] = sum_k xbar[b][k]*Wenc[h][k] + b_enc[h] ----
__global__ __launch_bounds__(256) void k_gemm(const u16* __restrict__ A,
                                              const u16* __restrict__ Bm,
                                              const float* __restrict__ b_enc,
                                              float* __restrict__ C) {
  __shared__ u16 lA[128 * 32];
  __shared__ u16 lB[128 * 32];
  const int tid = threadIdx.x;
  const int lane = tid & 63, wave = tid >> 6;
  const int wm = wave >> 1, wn = wave & 1;
  const int bx = blockIdx.x, by = blockIdx.y;

  const u16* gA0 = A + (size_t)(by * 128 + (tid >> 2)) * F_ + (tid & 3) * 8;
  const u16* gB0 = Bm + (size_t)(bx * 128 + (tid >> 2)) * F_ + (tid & 3) * 8;
  u16* lA0 = &lA[tid * 8];
  u16* lB0 = &lB[tid * 8];

  f32x4 acc[4][4] = {};
  const int lm = lane & 15;
  const int kq = (lane >> 4) * 8;

  for (int k0 = 0; k0 < F_; k0 += 32) {
    async16(gA0 + k0, lA0);
    async16(gA0 + 64 * F_ + k0, lA0 + 2048);
    async16(gB0 + k0, lB0);
    async16(gB0 + 64 * F_ + k0, lB0 + 2048);
    __syncthreads();
    bf16x8 av[4], bv[4];
#pragma unroll
    for (int i = 0; i < 4; ++i)
      av[i] = *(const bf16x8*)&lA[(wm * 64 + i * 16 + lm) * 32 + kq];
#pragma unroll
    for (int j = 0; j < 4; ++j)
      bv[j] = *(const bf16x8*)&lB[(wn * 64 + j * 16 + lm) * 32 + kq];
#pragma unroll
    for (int i = 0; i < 4; ++i)
#pragma unroll
      for (int j = 0; j < 4; ++j)
        acc[i][j] = __builtin_amdgcn_mfma_f32_16x16x32_bf16(av[i], bv[j], acc[i][j], 0, 0, 0);
    __syncthreads();
  }

#pragma unroll
  for (int i = 0; i < 4; ++i) {
    int rowg = by * 128 + wm * 64 + i * 16 + (lane >> 4) * 4;
#pragma unroll
    for (int j = 0; j < 4; ++j) {
      int colg = bx * 128 + wn * 64 + j * 16 + lm;
      float be = b_enc[colg];
      float* cp = C + (size_t)rowg * H_ + colg;
#pragma unroll
      for (int r = 0; r < 4; ++r) cp[(size_t)r * H_] = acc[i][j][r] + be;
    }
  }
}

// ---- K2: per-row histogram select (float4 passes, 2-level scan), zero row ----
__global__ __launch_bounds__(256) void k_select(float* __restrict__ a,
                                               int* __restrict__ candIdx,
                                               int* __restrict__ candCnt) {
  const int row = blockIdx.x, tid = threadIdx.x;
  float* arow = a + (size_t)row * H_;
  __shared__ int hist[NBINS];
  __shared__ int coarse[256];
  __shared__ float s_cut;
  __shared__ int s_cnt;
  for (int i = tid; i < NBINS; i += 256) hist[i] = 0;
  if (tid == 0) s_cnt = 0;
  __syncthreads();
  const float4* arow4 = (const float4*)arow;
#pragma unroll 4
  for (int i = tid; i < H_ / 4; i += 256) {
    float4 v = arow4[i];
    float vv[4] = {v.x, v.y, v.z, v.w};
#pragma unroll
    for (int c = 0; c < 4; ++c) {
      int b = (int)floorf((vv[c] + 4.0f) * 256.0f);
      b = b < 0 ? 0 : (b > NBINS - 1 ? NBINS - 1 : b);
      atomicAdd(&hist[b], 1);
    }
  }
  __syncthreads();
  {  // coarse sums: thread t owns bins [t*8, t*8+8)
    int s = 0;
#pragma unroll
    for (int j = 0; j < 8; ++j) s += hist[tid * 8 + j];
    coarse[tid] = s;
  }
  __syncthreads();
  if (tid == 0) {
    int c = 0, ifound = 0;
    for (int t = 255; t >= 0; --t) {
      if (c + coarse[t] >= TOPK) {
        for (int b = t * 8 + 7; b >= t * 8; --b) {
          c += hist[b];
          if (c >= TOPK) { ifound = b; break; }
        }
        break;
      }
      c += coarse[t];
    }
    s_cut = ((float)ifound * (1.0f / 256.0f) - 4.0f) - 0.025f;
  }
  __syncthreads();
  const float cut = s_cut;
  const float4 z4 = {0.f, 0.f, 0.f, 0.f};
  for (int i = tid; i < H_ / 4; i += 256) {
    float4 v = arow4[i];
    float vv[4] = {v.x, v.y, v.z, v.w};
#pragma unroll
    for (int c = 0; c < 4; ++c) {
      if (vv[c] >= cut) {
        int p = atomicAdd(&s_cnt, 1);
        if (p < MAXC) candIdx[row * MAXC + p] = i * 4 + c;
      }
    }
    ((float4*)arow)[i] = z4;  // same thread read-then-zero: safe
  }
  __syncthreads();
  if (tid == 0) candCnt[row] = s_cnt < MAXC ? s_cnt : MAXC;
}

// ---- K3: fp64 refinement, 4 candidates per wave for MLP/ILP ----
__global__ __launch_bounds__(256) void k_refine(const float* __restrict__ x,
                                               const float* __restrict__ b_dec,
                                               const float* __restrict__ Wenc,
                                               const float* __restrict__ b_enc,
                                               const int* __restrict__ candIdx,
                                               const int* __restrict__ candCnt,
                                               float* __restrict__ f,
                                               int* __restrict__ decIdx,
                                               float* __restrict__ decVal) {
  const int row = blockIdx.x, tid = threadIdx.x;
  const int lane = tid & 63, wave = tid >> 6;
  __shared__ double xl[F_];
  __shared__ double vals[MAXC];
  __shared__ int idxs[MAXC];
  for (int k = tid; k < F_; k += 256)
    xl[k] = (double)x[(size_t)row * F_ + k] - (double)b_dec[k];
  const int cnt = candCnt[row];
  for (int c = tid; c < cnt; c += 256) idxs[c] = candIdx[row * MAXC + c];
  __syncthreads();

  // 4 candidates per wave per iteration: 4 independent fp64 chains,
  // unroll-4 k-loop => ~16 global loads + 4 ds_reads in flight per wave.
  for (int cbase = wave * 4; cbase < cnt; cbase += 16) {
    const int n = (cnt - cbase) < 4 ? (cnt - cbase) : 4;
    int h[4];
#pragma unroll
    for (int j = 0; j < 4; ++j) h[j] = idxs[cbase + (j < n ? j : 0)];
    const float* w0 = Wenc + (size_t)h[0] * F_;
    const float* w1 = Wenc + (size_t)h[1] * F_;
    const float* w2 = Wenc + (size_t)h[2] * F_;
    const float* w3 = Wenc + (size_t)h[3] * F_;
    double s0 = 0.0, s1 = 0.0, s2 = 0.0, s3 = 0.0;
#pragma unroll 4
    for (int kk = 0; kk < 16; ++kk) {
      const int k = lane + kk * 64;
      const double xv = xl[k];
      s0 += xv * (double)w0[k];
      s1 += xv * (double)w1[k];
      s2 += xv * (double)w2[k];
      s3 += xv * (double)w3[k];
    }
#pragma unroll
    for (int off = 32; off > 0; off >>= 1) {
      s0 += __shfl_xor(s0, off);
      s1 += __shfl_xor(s1, off);
      s2 += __shfl_xor(s2, off);
      s3 += __shfl_xor(s3, off);
    }
    if (lane == 0) {
      double sv[4] = {s0, s1, s2, s3};
#pragma unroll
      for (int j = 0; j < 4; ++j)
        if (j < n) vals[cbase + j] = sv[j] + (double)b_enc[h[j]];
    }
  }
  __syncthreads();

  for (int c = tid; c < cnt; c += 256) {
    const double v = vals[c];
    const int h = idxs[c];
    int rank = 0;
    for (int o = 0; o < cnt; ++o) {
      double vo = vals[o];
      rank += (vo > v) || (vo == v && idxs[o] < h);  // jax tie-break: lower idx first
    }
    if (rank < TOPK) {
      float fv = v > 0.0 ? (float)v : 0.0f;
      f[(size_t)row * H_ + h] = fv;
      decIdx[row * TOPK + rank] = h;
      decVal[row * TOPK + rank] = fv;
    }
  }
}

// ---- K4: sparse decode: xhat[b,:] = sum_j val_j * W_decT[idx_j,:] + b_dec ----
__global__ __launch_bounds__(256) void k_decode(const int* __restrict__ decIdx,
                                               const float* __restrict__ decVal,
                                               const u16* __restrict__ WdecT,
                                               const float* __restrict__ b_dec,
                                               float* __restrict__ xhat) {
  const int row = blockIdx.x, tid = threadIdx.x;
  __shared__ int sIdx[TOPK];
  __shared__ float sVal[TOPK];
  if (tid < TOPK) {
    sIdx[tid] = decIdx[row * TOPK + tid];
    sVal[tid] = decVal[row * TOPK + tid];
  }
  __syncthreads();
  const int fb = tid * 4;
  float4 bd = *(const float4*)(b_dec + fb);
  float a0 = bd.x, a1 = bd.y, a2 = bd.z, a3 = bd.w;
#pragma unroll 8
  for (int j = 0; j < TOPK; ++j) {
    const float v = sVal[j];
    const ushort4 w = *(const ushort4*)(WdecT + (size_t)sIdx[j] * F_ + fb);
    a0 += v * bf2f(w.x); a1 += v * bf2f(w.y);
    a2 += v * bf2f(w.z); a3 += v * bf2f(w.w);
  }
  float4 o; o.x = a0; o.y = a1; o.z = a2; o.w = a3;
  *(float4*)(xhat + (size_t)row * F_ + fb) = o;
}

extern "C" void kernel_launch(void* const* d_in, const int* in_sizes, int n_in,
                              void* d_out, int out_size, void* d_ws, size_t ws_size,
                              hipStream_t stream) {
  const float* x    = (const float*)d_in[0];
  const float* Wenc = (const float*)d_in[1];
  const float* benc = (const float*)d_in[2];
  const float* Wdec = (const float*)d_in[3];
  const float* bdec = (const float*)d_in[4];

  float* out  = (float*)d_out;
  float* f    = out;                       // [4096][16384]
  float* xhat = out + (size_t)B_ * H_;     // [4096][1024]

  char* ws = (char*)d_ws;
  u16*  xbar    = (u16*)ws;                             // 8 MB
  u16*  wencb   = (u16*)(ws + (size_t)(8)  * 1048576);  // 32 MB
  u16*  wdecT   = (u16*)(ws + (size_t)(40) * 1048576);  // 32 MB
  int*  candIdx = (int*)(ws + (size_t)(72) * 1048576);  // 3 MB
  int*  candCnt = (int*)(ws + (size_t)(75) * 1048576);  // 16 KB
  int*  decIdx  = (int*)(ws + (size_t)(76) * 1048576);  // 1 MB
  float* decVal = (float*)(ws + (size_t)(77) * 1048576);// 1 MB

  k_xbar<<<B_ * F_ / 1024, 256, 0, stream>>>(x, bdec, xbar);
  k_cast<<<H_ * F_ / 1024, 256, 0, stream>>>(Wenc, wencb);
  k_transpose<<<dim3(H_ / 32, F_ / 32), 256, 0, stream>>>(Wdec, wdecT);
  k_gemm<<<dim3(H_ / 128, B_ / 128), 256, 0, stream>>>(xbar, wencb, benc, f);
  k_select<<<B_, 256, 0, stream>>>(f, candIdx, candCnt);
  k_refine<<<B_, 256, 0, stream>>>(x, bdec, Wenc, benc, candIdx, candCnt, f, decIdx, decVal);
  k_decode<<<B_, 256, 0, stream>>>(decIdx, decVal, wdecT, bdec, xhat);
}

// Round 3
// 910.851 us; speedup vs baseline: 1.2539x; 1.1072x over previous
//
#include <hip/hip_runtime.h>
#include <cstdint>

#define B_ 4096
#define F_ 1024
#define H_ 16384
#define TOPK 64
#define MAXC 192
#define NBINS 2048

typedef unsigned short u16;
typedef __attribute__((ext_vector_type(8))) short bf16x8;
typedef __attribute__((ext_vector_type(4))) float f32x4;

__device__ __forceinline__ u16 f2bf(float f) {
  union { float f; uint32_t u; } v; v.f = f;
  uint32_t u = v.u;
  uint32_t r = u + 0x7FFFu + ((u >> 16) & 1u);
  return (u16)(r >> 16);
}
__device__ __forceinline__ float bf2f(u16 h) {
  union { uint32_t u; float f; } v; v.u = ((uint32_t)h) << 16; return v.f;
}

__device__ __forceinline__ void async16(const void* g, void* l) {
  __builtin_amdgcn_global_load_lds(
      reinterpret_cast<const __attribute__((address_space(1))) uint32_t*>(
          reinterpret_cast<uintptr_t>(g)),
      reinterpret_cast<__attribute__((address_space(3))) uint32_t*>(
          reinterpret_cast<uintptr_t>(l)),
      16, 0, 0);
}

// ---- K0a: xbar = bf16(x - b_dec) ----
__global__ __launch_bounds__(256) void k_xbar(const float* __restrict__ x,
                                              const float* __restrict__ b_dec,
                                              u16* __restrict__ xbar) {
  int i = blockIdx.x * 256 + threadIdx.x;
  int base = i * 4;
  int col = base & (F_ - 1);
  float4 xv = *(const float4*)(x + base);
  float4 bv = *(const float4*)(b_dec + col);
  ushort4 o;
  o.x = f2bf(xv.x - bv.x); o.y = f2bf(xv.y - bv.y);
  o.z = f2bf(xv.z - bv.z); o.w = f2bf(xv.w - bv.w);
  *(ushort4*)(xbar + base) = o;
}

// ---- K0b: bf16 cast of W_enc ----
__global__ __launch_bounds__(256) void k_cast(const float* __restrict__ src,
                                              u16* __restrict__ dst) {
  size_t base = (size_t)(blockIdx.x * 256 + threadIdx.x) * 4;
  float4 v = *(const float4*)(src + base);
  ushort4 o; o.x = f2bf(v.x); o.y = f2bf(v.y); o.z = f2bf(v.z); o.w = f2bf(v.w);
  *(ushort4*)(dst + base) = o;
}

// ---- K0c: W_dec [F,H] fp32 -> W_decT [H,F] bf16 ----
__global__ __launch_bounds__(256) void k_transpose(const float* __restrict__ Wdec,
                                                   u16* __restrict__ WdecT) {
  __shared__ float tile[32][33];
  int hb = blockIdx.x * 32, fb = blockIdx.y * 32;
  int tx = threadIdx.x & 31, ty = threadIdx.x >> 5;  // ty 0..7
#pragma unroll
  for (int i = 0; i < 32; i += 8)
    tile[ty + i][tx] = Wdec[(size_t)(fb + ty + i) * H_ + hb + tx];
  __syncthreads();
#pragma unroll
  for (int i = 0; i < 32; i += 8)
    WdecT[(size_t)(hb + ty + i) * F_ + fb + tx] = f2bf(tile[tx][ty + i]);
}

// ---- K1: bf16 MFMA GEMM: a[b][h] = sum_k xbar[b][k]*Wenc[h][k] + b_enc[h] ----
__global__ __launch_bounds__(256) void k_gemm(const u16* __restrict__ A,
                                              const u16* __restrict__ Bm,
                                              const float* __restrict__ b_enc,
                                              float* __restrict__ C) {
  __shared__ u16 lA[128 * 32];
  __shared__ u16 lB[128 * 32];
  const int tid = threadIdx.x;
  const int lane = tid & 63, wave = tid >> 6;
  const int wm = wave >> 1, wn = wave & 1;
  const int bx = blockIdx.x, by = blockIdx.y;

  const u16* gA0 = A + (size_t)(by * 128 + (tid >> 2)) * F_ + (tid & 3) * 8;
  const u16* gB0 = Bm + (size_t)(bx * 128 + (tid >> 2)) * F_ + (tid & 3) * 8;
  u16* lA0 = &lA[tid * 8];
  u16* lB0 = &lB[tid * 8];

  f32x4 acc[4][4] = {};
  const int lm = lane & 15;
  const int kq = (lane >> 4) * 8;

  for (int k0 = 0; k0 < F_; k0 += 32) {
    async16(gA0 + k0, lA0);
    async16(gA0 + 64 * F_ + k0, lA0 + 2048);
    async16(gB0 + k0, lB0);
    async16(gB0 + 64 * F_ + k0, lB0 + 2048);
    __syncthreads();
    bf16x8 av[4], bv[4];
#pragma unroll
    for (int i = 0; i < 4; ++i)
      av[i] = *(const bf16x8*)&lA[(wm * 64 + i * 16 + lm) * 32 + kq];
#pragma unroll
    for (int j = 0; j < 4; ++j)
      bv[j] = *(const bf16x8*)&lB[(wn * 64 + j * 16 + lm) * 32 + kq];
#pragma unroll
    for (int i = 0; i < 4; ++i)
#pragma unroll
      for (int j = 0; j < 4; ++j)
        acc[i][j] = __builtin_amdgcn_mfma_f32_16x16x32_bf16(av[i], bv[j], acc[i][j], 0, 0, 0);
    __syncthreads();
  }

#pragma unroll
  for (int i = 0; i < 4; ++i) {
    int rowg = by * 128 + wm * 64 + i * 16 + (lane >> 4) * 4;
#pragma unroll
    for (int j = 0; j < 4; ++j) {
      int colg = bx * 128 + wn * 64 + j * 16 + lm;
      float be = b_enc[colg];
      float* cp = C + (size_t)rowg * H_ + colg;
#pragma unroll
      for (int r = 0; r < 4; ++r) cp[(size_t)r * H_] = acc[i][j][r] + be;
    }
  }
}

// ---- K2: per-row histogram select (float4 passes, 2-level scan), zero row ----
__global__ __launch_bounds__(256) void k_select(float* __restrict__ a,
                                               int* __restrict__ candIdx,
                                               int* __restrict__ candCnt) {
  const int row = blockIdx.x, tid = threadIdx.x;
  float* arow = a + (size_t)row * H_;
  __shared__ int hist[NBINS];
  __shared__ int coarse[256];
  __shared__ float s_cut;
  __shared__ int s_cnt;
  for (int i = tid; i < NBINS; i += 256) hist[i] = 0;
  if (tid == 0) s_cnt = 0;
  __syncthreads();
  const float4* arow4 = (const float4*)arow;
#pragma unroll 4
  for (int i = tid; i < H_ / 4; i += 256) {
    float4 v = arow4[i];
    float vv[4] = {v.x, v.y, v.z, v.w};
#pragma unroll
    for (int c = 0; c < 4; ++c) {
      int b = (int)floorf((vv[c] + 4.0f) * 256.0f);
      b = b < 0 ? 0 : (b > NBINS - 1 ? NBINS - 1 : b);
      atomicAdd(&hist[b], 1);
    }
  }
  __syncthreads();
  {
    int s = 0;
#pragma unroll
    for (int j = 0; j < 8; ++j) s += hist[tid * 8 + j];
    coarse[tid] = s;
  }
  __syncthreads();
  if (tid == 0) {
    int c = 0, ifound = 0;
    for (int t = 255; t >= 0; --t) {
      if (c + coarse[t] >= TOPK) {
        for (int b = t * 8 + 7; b >= t * 8; --b) {
          c += hist[b];
          if (c >= TOPK) { ifound = b; break; }
        }
        break;
      }
      c += coarse[t];
    }
    s_cut = ((float)ifound * (1.0f / 256.0f) - 4.0f) - 0.025f;
  }
  __syncthreads();
  const float cut = s_cut;
  const float4 z4 = {0.f, 0.f, 0.f, 0.f};
  for (int i = tid; i < H_ / 4; i += 256) {
    float4 v = arow4[i];
    float vv[4] = {v.x, v.y, v.z, v.w};
#pragma unroll
    for (int c = 0; c < 4; ++c) {
      if (vv[c] >= cut) {
        int p = atomicAdd(&s_cnt, 1);
        if (p < MAXC) candIdx[row * MAXC + p] = i * 4 + c;
      }
    }
    ((float4*)arow)[i] = z4;  // same thread read-then-zero: safe
  }
  __syncthreads();
  if (tid == 0) candCnt[row] = s_cnt < MAXC ? s_cnt : MAXC;
}

// ---- K3: fp64 refinement. x in registers; candidate rows via float4 gathers.
// 2 candidates in flight per wave = 8 global_load_dwordx4 outstanding.
__global__ __launch_bounds__(256) void k_refine(const float* __restrict__ x,
                                               const float* __restrict__ b_dec,
                                               const float* __restrict__ Wenc,
                                               const float* __restrict__ b_enc,
                                               const int* __restrict__ candIdx,
                                               const int* __restrict__ candCnt,
                                               float* __restrict__ f,
                                               int* __restrict__ decIdx,
                                               float* __restrict__ decVal) {
  const int row = blockIdx.x, tid = threadIdx.x;
  const int lane = tid & 63, wave = tid >> 6;
  __shared__ double xl[F_];
  __shared__ double vals[MAXC];
  __shared__ int idxs[MAXC];
  for (int k = tid; k < F_; k += 256)
    xl[k] = (double)x[(size_t)row * F_ + k] - (double)b_dec[k];
  const int cnt = candCnt[row];
  for (int c = tid; c < cnt; c += 256) idxs[c] = candIdx[row * MAXC + c];
  __syncthreads();

  // candidate-invariant x slice -> registers (16 doubles/lane)
  double xr[16];
#pragma unroll
  for (int ch = 0; ch < 4; ++ch)
#pragma unroll
    for (int j = 0; j < 4; ++j)
      xr[ch * 4 + j] = xl[ch * 256 + lane * 4 + j];

  for (int cbase = wave * 2; cbase < cnt; cbase += 8) {
    const int n = (cnt - cbase) < 2 ? (cnt - cbase) : 2;
    const int h0 = idxs[cbase];
    const int h1 = idxs[cbase + (n > 1 ? 1 : 0)];
    const float4* w0 = (const float4*)(Wenc + (size_t)h0 * F_);
    const float4* w1 = (const float4*)(Wenc + (size_t)h1 * F_);
    float4 a0[4], a1[4];
#pragma unroll
    for (int ch = 0; ch < 4; ++ch) a0[ch] = w0[ch * 64 + lane];
#pragma unroll
    for (int ch = 0; ch < 4; ++ch) a1[ch] = w1[ch * 64 + lane];
    double s0 = 0.0, s1 = 0.0;
#pragma unroll
    for (int ch = 0; ch < 4; ++ch) {
      s0 += xr[ch * 4 + 0] * (double)a0[ch].x;
      s0 += xr[ch * 4 + 1] * (double)a0[ch].y;
      s0 += xr[ch * 4 + 2] * (double)a0[ch].z;
      s0 += xr[ch * 4 + 3] * (double)a0[ch].w;
      s1 += xr[ch * 4 + 0] * (double)a1[ch].x;
      s1 += xr[ch * 4 + 1] * (double)a1[ch].y;
      s1 += xr[ch * 4 + 2] * (double)a1[ch].z;
      s1 += xr[ch * 4 + 3] * (double)a1[ch].w;
    }
#pragma unroll
    for (int off = 32; off > 0; off >>= 1) {
      s0 += __shfl_xor(s0, off);
      s1 += __shfl_xor(s1, off);
    }
    if (lane == 0) {
      vals[cbase] = s0 + (double)b_enc[h0];
      if (n > 1) vals[cbase + 1] = s1 + (double)b_enc[h1];
    }
  }
  __syncthreads();

  for (int c = tid; c < cnt; c += 256) {
    const double v = vals[c];
    const int h = idxs[c];
    int rank = 0;
    for (int o = 0; o < cnt; ++o) {
      double vo = vals[o];
      rank += (vo > v) || (vo == v && idxs[o] < h);  // jax tie-break: lower idx first
    }
    if (rank < TOPK) {
      float fv = v > 0.0 ? (float)v : 0.0f;
      f[(size_t)row * H_ + h] = fv;
      decIdx[row * TOPK + rank] = h;
      decVal[row * TOPK + rank] = fv;
    }
  }
}

// ---- K4: sparse decode: xhat[b,:] = sum_j val_j * W_decT[idx_j,:] + b_dec ----
__global__ __launch_bounds__(256) void k_decode(const int* __restrict__ decIdx,
                                               const float* __restrict__ decVal,
                                               const u16* __restrict__ WdecT,
                                               const float* __restrict__ b_dec,
                                               float* __restrict__ xhat) {
  const int row = blockIdx.x, tid = threadIdx.x;
  __shared__ int sIdx[TOPK];
  __shared__ float sVal[TOPK];
  if (tid < TOPK) {
    sIdx[tid] = decIdx[row * TOPK + tid];
    sVal[tid] = decVal[row * TOPK + tid];
  }
  __syncthreads();
  const int fb = tid * 4;
  float4 bd = *(const float4*)(b_dec + fb);
  float a0 = bd.x, a1 = bd.y, a2 = bd.z, a3 = bd.w;
#pragma unroll 8
  for (int j = 0; j < TOPK; ++j) {
    const float v = sVal[j];
    const ushort4 w = *(const ushort4*)(WdecT + (size_t)sIdx[j] * F_ + fb);
    a0 += v * bf2f(w.x); a1 += v * bf2f(w.y);
    a2 += v * bf2f(w.z); a3 += v * bf2f(w.w);
  }
  float4 o; o.x = a0; o.y = a1; o.z = a2; o.w = a3;
  *(float4*)(xhat + (size_t)row * F_ + fb) = o;
}

extern "C" void kernel_launch(void* const* d_in, const int* in_sizes, int n_in,
                              void* d_out, int out_size, void* d_ws, size_t ws_size,
                              hipStream_t stream) {
  const float* x    = (const float*)d_in[0];
  const float* Wenc = (const float*)d_in[1];
  const float* benc = (const float*)d_in[2];
  const float* Wdec = (const float*)d_in[3];
  const float* bdec = (const float*)d_in[4];

  float* out  = (float*)d_out;
  float* f    = out;                       // [4096][16384]
  float* xhat = out + (size_t)B_ * H_;     // [4096][1024]

  char* ws = (char*)d_ws;
  u16*  xbar    = (u16*)ws;                             // 8 MB
  u16*  wencb   = (u16*)(ws + (size_t)(8)  * 1048576);  // 32 MB
  u16*  wdecT   = (u16*)(ws + (size_t)(40) * 1048576);  // 32 MB
  int*  candIdx = (int*)(ws + (size_t)(72) * 1048576);  // 3 MB
  int*  candCnt = (int*)(ws + (size_t)(75) * 1048576);  // 16 KB
  int*  decIdx  = (int*)(ws + (size_t)(76) * 1048576);  // 1 MB
  float* decVal = (float*)(ws + (size_t)(77) * 1048576);// 1 MB

  k_xbar<<<B_ * F_ / 1024, 256, 0, stream>>>(x, bdec, xbar);
  k_cast<<<H_ * F_ / 1024, 256, 0, stream>>>(Wenc, wencb);
  k_transpose<<<dim3(H_ / 32, F_ / 32), 256, 0, stream>>>(Wdec, wdecT);
  k_gemm<<<dim3(H_ / 128, B_ / 128), 256, 0, stream>>>(xbar, wencb, benc, f);
  k_select<<<B_, 256, 0, stream>>>(f, candIdx, candCnt);
  k_refine<<<B_, 256, 0, stream>>>(x, bdec, Wenc, benc, candIdx, candCnt, f, decIdx, decVal);
  k_decode<<<B_, 256, 0, stream>>>(decIdx, decVal, wdecT, bdec, xhat);
}

// Round 5
// 899.410 us; speedup vs baseline: 1.2699x; 1.0127x over previous
//
#include <hip/hip_runtime.h>
#include <cstdint>

#define B_ 4096
#define F_ 1024
#define H_ 16384
#define TOPK 64
#define MAXC 192
#define NBINS 2048

typedef unsigned short u16;
typedef __attribute__((ext_vector_type(8))) short bf16x8;
typedef __attribute__((ext_vector_type(4))) float f32x4;

__device__ __forceinline__ u16 f2bf(float f) {
  union { float f; uint32_t u; } v; v.f = f;
  uint32_t u = v.u;
  uint32_t r = u + 0x7FFFu + ((u >> 16) & 1u);
  return (u16)(r >> 16);
}
__device__ __forceinline__ float bf2f(u16 h) {
  union { uint32_t u; float f; } v; v.u = ((uint32_t)h) << 16; return v.f;
}

__device__ __forceinline__ void async16(const void* g, void* l) {
  __builtin_amdgcn_global_load_lds(
      reinterpret_cast<const __attribute__((address_space(1))) uint32_t*>(
          reinterpret_cast<uintptr_t>(g)),
      reinterpret_cast<__attribute__((address_space(3))) uint32_t*>(
          reinterpret_cast<uintptr_t>(l)),
      16, 0, 0);
}

// ---- K0a: xbar = bf16(x - b_dec) ----
__global__ __launch_bounds__(256) void k_xbar(const float* __restrict__ x,
                                              const float* __restrict__ b_dec,
                                              u16* __restrict__ xbar) {
  int i = blockIdx.x * 256 + threadIdx.x;
  int base = i * 4;
  int col = base & (F_ - 1);
  float4 xv = *(const float4*)(x + base);
  float4 bv = *(const float4*)(b_dec + col);
  ushort4 o;
  o.x = f2bf(xv.x - bv.x); o.y = f2bf(xv.y - bv.y);
  o.z = f2bf(xv.z - bv.z); o.w = f2bf(xv.w - bv.w);
  *(ushort4*)(xbar + base) = o;
}

// ---- K0b: bf16 cast of W_enc ----
__global__ __launch_bounds__(256) void k_cast(const float* __restrict__ src,
                                              u16* __restrict__ dst) {
  size_t base = (size_t)(blockIdx.x * 256 + threadIdx.x) * 4;
  float4 v = *(const float4*)(src + base);
  ushort4 o; o.x = f2bf(v.x); o.y = f2bf(v.y); o.z = f2bf(v.z); o.w = f2bf(v.w);
  *(ushort4*)(dst + base) = o;
}

// ---- K0c: W_dec [F,H] fp32 -> W_decT [H,F] bf16 ----
__global__ __launch_bounds__(256) void k_transpose(const float* __restrict__ Wdec,
                                                   u16* __restrict__ WdecT) {
  __shared__ float tile[32][33];
  int hb = blockIdx.x * 32, fb = blockIdx.y * 32;
  int tx = threadIdx.x & 31, ty = threadIdx.x >> 5;  // ty 0..7
#pragma unroll
  for (int i = 0; i < 32; i += 8)
    tile[ty + i][tx] = Wdec[(size_t)(fb + ty + i) * H_ + hb + tx];
  __syncthreads();
#pragma unroll
  for (int i = 0; i < 32; i += 8)
    WdecT[(size_t)(hb + ty + i) * F_ + fb + tx] = f2bf(tile[tx][ty + i]);
}

// ---- K1: bf16 MFMA GEMM with XOR-swizzled LDS (kills 8-way b128 bank conflicts).
// Data (row,kc) lives at LDS slot row*4 + (kc ^ ((row>>1)&3)); staging achieves
// this by permuting the GLOBAL source chunk per thread (LDS dest must stay
// lane-ordered for global_load_lds).
__global__ __launch_bounds__(256) void k_gemm(const u16* __restrict__ A,
                                              const u16* __restrict__ Bm,
                                              const float* __restrict__ b_enc,
                                              float* __restrict__ C) {
  __shared__ u16 lA[128 * 32];
  __shared__ u16 lB[128 * 32];
  const int tid = threadIdx.x;
  const int lane = tid & 63, wave = tid >> 6;
  const int wm = wave >> 1, wn = wave & 1;
  const int bx = blockIdx.x, by = blockIdx.y;

  const int kcs = (tid & 3) ^ ((tid >> 3) & 3);  // swizzled source chunk
  const u16* gA0 = A + (size_t)(by * 128 + (tid >> 2)) * F_ + kcs * 8;
  const u16* gB0 = Bm + (size_t)(bx * 128 + (tid >> 2)) * F_ + kcs * 8;
  u16* lA0 = &lA[tid * 8];
  u16* lB0 = &lB[tid * 8];

  f32x4 acc[4][4] = {};
  const int lm = lane & 15;
  const int kcp = (((lane >> 4) ^ ((lm >> 1) & 3))) * 8;  // swizzled read offset

  for (int k0 = 0; k0 < F_; k0 += 32) {
    async16(gA0 + k0, lA0);
    async16(gA0 + 64 * F_ + k0, lA0 + 2048);
    async16(gB0 + k0, lB0);
    async16(gB0 + 64 * F_ + k0, lB0 + 2048);
    __syncthreads();
    bf16x8 av[4], bv[4];
#pragma unroll
    for (int i = 0; i < 4; ++i)
      av[i] = *(const bf16x8*)&lA[(wm * 64 + i * 16 + lm) * 32 + kcp];
#pragma unroll
    for (int j = 0; j < 4; ++j)
      bv[j] = *(const bf16x8*)&lB[(wn * 64 + j * 16 + lm) * 32 + kcp];
#pragma unroll
    for (int i = 0; i < 4; ++i)
#pragma unroll
      for (int j = 0; j < 4; ++j)
        acc[i][j] = __builtin_amdgcn_mfma_f32_16x16x32_bf16(av[i], bv[j], acc[i][j], 0, 0, 0);
    __syncthreads();
  }

#pragma unroll
  for (int i = 0; i < 4; ++i) {
    int rowg = by * 128 + wm * 64 + i * 16 + (lane >> 4) * 4;
#pragma unroll
    for (int j = 0; j < 4; ++j) {
      int colg = bx * 128 + wn * 64 + j * 16 + lm;
      float be = b_enc[colg];
      float* cp = C + (size_t)rowg * H_ + colg;
#pragma unroll
      for (int r = 0; r < 4; ++r)
        __builtin_nontemporal_store(acc[i][j][r] + be, cp + (size_t)r * H_);
    }
  }
}

// ---- K2: per-row histogram select (float4 passes, 2-level scan), zero row ----
__global__ __launch_bounds__(256) void k_select(float* __restrict__ a,
                                               int* __restrict__ candIdx,
                                               int* __restrict__ candCnt) {
  const int row = blockIdx.x, tid = threadIdx.x;
  float* arow = a + (size_t)row * H_;
  __shared__ int hist[NBINS];
  __shared__ int coarse[256];
  __shared__ float s_cut;
  __shared__ int s_cnt;
  for (int i = tid; i < NBINS; i += 256) hist[i] = 0;
  if (tid == 0) s_cnt = 0;
  __syncthreads();
  const float4* arow4 = (const float4*)arow;
#pragma unroll 4
  for (int i = tid; i < H_ / 4; i += 256) {
    float4 v = arow4[i];
    float vv[4] = {v.x, v.y, v.z, v.w};
#pragma unroll
    for (int c = 0; c < 4; ++c) {
      int b = (int)floorf((vv[c] + 4.0f) * 256.0f);
      b = b < 0 ? 0 : (b > NBINS - 1 ? NBINS - 1 : b);
      atomicAdd(&hist[b], 1);
    }
  }
  __syncthreads();
  {
    int s = 0;
#pragma unroll
    for (int j = 0; j < 8; ++j) s += hist[tid * 8 + j];
    coarse[tid] = s;
  }
  __syncthreads();
  if (tid == 0) {
    int c = 0, ifound = 0;
    for (int t = 255; t >= 0; --t) {
      if (c + coarse[t] >= TOPK) {
        for (int b = t * 8 + 7; b >= t * 8; --b) {
          c += hist[b];
          if (c >= TOPK) { ifound = b; break; }
        }
        break;
      }
      c += coarse[t];
    }
    s_cut = ((float)ifound * (1.0f / 256.0f) - 4.0f) - 0.025f;
  }
  __syncthreads();
  const float cut = s_cut;
  const f32x4 z4 = {0.f, 0.f, 0.f, 0.f};
  for (int i = tid; i < H_ / 4; i += 256) {
    float4 v = arow4[i];
    float vv[4] = {v.x, v.y, v.z, v.w};
#pragma unroll
    for (int c = 0; c < 4; ++c) {
      if (vv[c] >= cut) {
        int p = atomicAdd(&s_cnt, 1);
        if (p < MAXC) candIdx[row * MAXC + p] = i * 4 + c;
      }
    }
    __builtin_nontemporal_store(z4, (f32x4*)arow + i);  // same thread read-then-zero
  }
  __syncthreads();
  if (tid == 0) candCnt[row] = s_cnt < MAXC ? s_cnt : MAXC;
}

// ---- K3: fp64 refinement. x in registers; 4 candidates per wave batch:
// all 16 global_load_dwordx4 issued before the fp64 phase (max MLP).
__global__ __launch_bounds__(256) void k_refine(const float* __restrict__ x,
                                               const float* __restrict__ b_dec,
                                               const float* __restrict__ Wenc,
                                               const float* __restrict__ b_enc,
                                               const int* __restrict__ candIdx,
                                               const int* __restrict__ candCnt,
                                               float* __restrict__ f,
                                               int* __restrict__ decIdx,
                                               float* __restrict__ decVal) {
  const int row = blockIdx.x, tid = threadIdx.x;
  const int lane = tid & 63, wave = tid >> 6;
  __shared__ double xl[F_];
  __shared__ double vals[MAXC];
  __shared__ int idxs[MAXC];
  for (int k = tid; k < F_; k += 256)
    xl[k] = (double)x[(size_t)row * F_ + k] - (double)b_dec[k];
  const int cnt = candCnt[row];
  for (int c = tid; c < cnt; c += 256) idxs[c] = candIdx[row * MAXC + c];
  __syncthreads();

  // candidate-invariant x slice -> registers (16 doubles/lane)
  double xr[16];
#pragma unroll
  for (int ch = 0; ch < 4; ++ch)
#pragma unroll
    for (int j = 0; j < 4; ++j)
      xr[ch * 4 + j] = xl[ch * 256 + lane * 4 + j];

  for (int cbase = wave * 4; cbase < cnt; cbase += 16) {
    const int n = (cnt - cbase) < 4 ? (cnt - cbase) : 4;
    int h[4];
#pragma unroll
    for (int j = 0; j < 4; ++j) h[j] = idxs[cbase + (j < n ? j : 0)];
    float4 aw[4][4];
#pragma unroll
    for (int j = 0; j < 4; ++j) {
      const float4* wj = (const float4*)(Wenc + (size_t)h[j] * F_);
#pragma unroll
      for (int ch = 0; ch < 4; ++ch) aw[j][ch] = wj[ch * 64 + lane];
    }
    double s[4] = {0.0, 0.0, 0.0, 0.0};
#pragma unroll
    for (int j = 0; j < 4; ++j)
#pragma unroll
      for (int ch = 0; ch < 4; ++ch) {
        s[j] += xr[ch * 4 + 0] * (double)aw[j][ch].x;
        s[j] += xr[ch * 4 + 1] * (double)aw[j][ch].y;
        s[j] += xr[ch * 4 + 2] * (double)aw[j][ch].z;
        s[j] += xr[ch * 4 + 3] * (double)aw[j][ch].w;
      }
#pragma unroll
    for (int off = 32; off > 0; off >>= 1) {
#pragma unroll
      for (int j = 0; j < 4; ++j) s[j] += __shfl_xor(s[j], off);
    }
    if (lane == 0) {
#pragma unroll
      for (int j = 0; j < 4; ++j)
        if (j < n) vals[cbase + j] = s[j] + (double)b_enc[h[j]];
    }
  }
  __syncthreads();

  for (int c = tid; c < cnt; c += 256) {
    const double v = vals[c];
    const int h = idxs[c];
    int rank = 0;
    for (int o = 0; o < cnt; ++o) {
      double vo = vals[o];
      rank += (vo > v) || (vo == v && idxs[o] < h);  // jax tie-break: lower idx first
    }
    if (rank < TOPK) {
      float fv = v > 0.0 ? (float)v : 0.0f;
      f[(size_t)row * H_ + h] = fv;
      decIdx[row * TOPK + rank] = h;
      decVal[row * TOPK + rank] = fv;
    }
  }
}

// ---- K4: sparse decode: xhat[b,:] = sum_j val_j * W_decT[idx_j,:] + b_dec ----
__global__ __launch_bounds__(256) void k_decode(const int* __restrict__ decIdx,
                                               const float* __restrict__ decVal,
                                               const u16* __restrict__ WdecT,
                                               const float* __restrict__ b_dec,
                                               float* __restrict__ xhat) {
  const int row = blockIdx.x, tid = threadIdx.x;
  __shared__ int sIdx[TOPK];
  __shared__ float sVal[TOPK];
  if (tid < TOPK) {
    sIdx[tid] = decIdx[row * TOPK + tid];
    sVal[tid] = decVal[row * TOPK + tid];
  }
  __syncthreads();
  const int fb = tid * 4;
  float4 bd = *(const float4*)(b_dec + fb);
  float a0 = bd.x, a1 = bd.y, a2 = bd.z, a3 = bd.w;
#pragma unroll 8
  for (int j = 0; j < TOPK; ++j) {
    const float v = sVal[j];
    const ushort4 w = *(const ushort4*)(WdecT + (size_t)sIdx[j] * F_ + fb);
    a0 += v * bf2f(w.x); a1 += v * bf2f(w.y);
    a2 += v * bf2f(w.z); a3 += v * bf2f(w.w);
  }
  float4 o; o.x = a0; o.y = a1; o.z = a2; o.w = a3;
  *(float4*)(xhat + (size_t)row * F_ + fb) = o;
}

extern "C" void kernel_launch(void* const* d_in, const int* in_sizes, int n_in,
                              void* d_out, int out_size, void* d_ws, size_t ws_size,
                              hipStream_t stream) {
  const float* x    = (const float*)d_in[0];
  const float* Wenc = (const float*)d_in[1];
  const float* benc = (const float*)d_in[2];
  const float* Wdec = (const float*)d_in[3];
  const float* bdec = (const float*)d_in[4];

  float* out  = (float*)d_out;
  float* f    = out;                       // [4096][16384]
  float* xhat = out + (size_t)B_ * H_;     // [4096][1024]

  char* ws = (char*)d_ws;
  u16*  xbar    = (u16*)ws;                             // 8 MB
  u16*  wencb   = (u16*)(ws + (size_t)(8)  * 1048576);  // 32 MB
  u16*  wdecT   = (u16*)(ws + (size_t)(40) * 1048576);  // 32 MB
  int*  candIdx = (int*)(ws + (size_t)(72) * 1048576);  // 3 MB
  int*  candCnt = (int*)(ws + (size_t)(75) * 1048576);  // 16 KB
  int*  decIdx  = (int*)(ws + (size_t)(76) * 1048576);  // 1 MB
  float* decVal = (float*)(ws + (size_t)(77) * 1048576);// 1 MB

  k_xbar<<<B_ * F_ / 1024, 256, 0, stream>>>(x, bdec, xbar);
  k_cast<<<H_ * F_ / 1024, 256, 0, stream>>>(Wenc, wencb);
  k_transpose<<<dim3(H_ / 32, F_ / 32), 256, 0, stream>>>(Wdec, wdecT);
  k_gemm<<<dim3(H_ / 128, B_ / 128), 256, 0, stream>>>(xbar, wencb, benc, f);
  k_select<<<B_, 256, 0, stream>>>(f, candIdx, candCnt);
  k_refine<<<B_, 256, 0, stream>>>(x, bdec, Wenc, benc, candIdx, candCnt, f, decIdx, decVal);
  k_decode<<<B_, 256, 0, stream>>>(decIdx, decVal, wdecT, bdec, xhat);
}

// Round 6
// 872.607 us; speedup vs baseline: 1.3089x; 1.0307x over previous
//
#include <hip/hip_runtime.h>
#include <cstdint>

#define B_ 4096
#define F_ 1024
#define H_ 16384
#define TOPK 64
#define MAXC 192
#define NBINS 2048

typedef unsigned short u16;
typedef __attribute__((ext_vector_type(8))) short bf16x8;
typedef __attribute__((ext_vector_type(8))) unsigned short u16x8;
typedef __attribute__((ext_vector_type(4))) float f32x4;

__device__ __forceinline__ u16 f2bf(float f) {
  union { float f; uint32_t u; } v; v.f = f;
  uint32_t u = v.u;
  uint32_t r = u + 0x7FFFu + ((u >> 16) & 1u);
  return (u16)(r >> 16);
}
__device__ __forceinline__ float bf2f(u16 h) {
  union { uint32_t u; float f; } v; v.u = ((uint32_t)h) << 16; return v.f;
}

__device__ __forceinline__ void async16(const void* g, void* l) {
  __builtin_amdgcn_global_load_lds(
      reinterpret_cast<const __attribute__((address_space(1))) uint32_t*>(
          reinterpret_cast<uintptr_t>(g)),
      reinterpret_cast<__attribute__((address_space(3))) uint32_t*>(
          reinterpret_cast<uintptr_t>(l)),
      16, 0, 0);
}

// ---- K0a: xbar = bf16(x - b_dec) ----
__global__ __launch_bounds__(256) void k_xbar(const float* __restrict__ x,
                                              const float* __restrict__ b_dec,
                                              u16* __restrict__ xbar) {
  int i = blockIdx.x * 256 + threadIdx.x;
  int base = i * 4;
  int col = base & (F_ - 1);
  float4 xv = *(const float4*)(x + base);
  float4 bv = *(const float4*)(b_dec + col);
  ushort4 o;
  o.x = f2bf(xv.x - bv.x); o.y = f2bf(xv.y - bv.y);
  o.z = f2bf(xv.z - bv.z); o.w = f2bf(xv.w - bv.w);
  *(ushort4*)(xbar + base) = o;
}

// ---- K0b: bf16 cast of W_enc ----
__global__ __launch_bounds__(256) void k_cast(const float* __restrict__ src,
                                              u16* __restrict__ dst) {
  size_t base = (size_t)(blockIdx.x * 256 + threadIdx.x) * 4;
  float4 v = *(const float4*)(src + base);
  ushort4 o; o.x = f2bf(v.x); o.y = f2bf(v.y); o.z = f2bf(v.z); o.w = f2bf(v.w);
  *(ushort4*)(dst + base) = o;
}

// ---- K0c: W_dec [F,H] fp32 -> W_decT [H,F] bf16 ----
__global__ __launch_bounds__(256) void k_transpose(const float* __restrict__ Wdec,
                                                   u16* __restrict__ WdecT) {
  __shared__ float tile[32][33];
  int hb = blockIdx.x * 32, fb = blockIdx.y * 32;
  int tx = threadIdx.x & 31, ty = threadIdx.x >> 5;  // ty 0..7
#pragma unroll
  for (int i = 0; i < 32; i += 8)
    tile[ty + i][tx] = Wdec[(size_t)(fb + ty + i) * H_ + hb + tx];
  __syncthreads();
#pragma unroll
  for (int i = 0; i < 32; i += 8)
    WdecT[(size_t)(hb + ty + i) * F_ + fb + tx] = f2bf(tile[tx][ty + i]);
}

// ---- K1: bf16 MFMA GEMM, XOR-swizzled LDS (conflict-free), bf16 output.
// Writes a[b][h] as bf16 (128 MB) — halves write traffic and select's read.
__global__ __launch_bounds__(256) void k_gemm(const u16* __restrict__ A,
                                              const u16* __restrict__ Bm,
                                              const float* __restrict__ b_enc,
                                              u16* __restrict__ Cbf) {
  __shared__ u16 lA[128 * 32];
  __shared__ u16 lB[128 * 32];
  const int tid = threadIdx.x;
  const int lane = tid & 63, wave = tid >> 6;
  const int wm = wave >> 1, wn = wave & 1;
  const int bx = blockIdx.x, by = blockIdx.y;

  const int kcs = (tid & 3) ^ ((tid >> 3) & 3);  // swizzled source chunk
  const u16* gA0 = A + (size_t)(by * 128 + (tid >> 2)) * F_ + kcs * 8;
  const u16* gB0 = Bm + (size_t)(bx * 128 + (tid >> 2)) * F_ + kcs * 8;
  u16* lA0 = &lA[tid * 8];
  u16* lB0 = &lB[tid * 8];

  f32x4 acc[4][4] = {};
  const int lm = lane & 15;
  const int kcp = (((lane >> 4) ^ ((lm >> 1) & 3))) * 8;  // swizzled read offset

  for (int k0 = 0; k0 < F_; k0 += 32) {
    async16(gA0 + k0, lA0);
    async16(gA0 + 64 * F_ + k0, lA0 + 2048);
    async16(gB0 + k0, lB0);
    async16(gB0 + 64 * F_ + k0, lB0 + 2048);
    __syncthreads();
    bf16x8 av[4], bv[4];
#pragma unroll
    for (int i = 0; i < 4; ++i)
      av[i] = *(const bf16x8*)&lA[(wm * 64 + i * 16 + lm) * 32 + kcp];
#pragma unroll
    for (int j = 0; j < 4; ++j)
      bv[j] = *(const bf16x8*)&lB[(wn * 64 + j * 16 + lm) * 32 + kcp];
#pragma unroll
    for (int i = 0; i < 4; ++i)
#pragma unroll
      for (int j = 0; j < 4; ++j)
        acc[i][j] = __builtin_amdgcn_mfma_f32_16x16x32_bf16(av[i], bv[j], acc[i][j], 0, 0, 0);
    __syncthreads();
  }

#pragma unroll
  for (int i = 0; i < 4; ++i) {
    int rowg = by * 128 + wm * 64 + i * 16 + (lane >> 4) * 4;
#pragma unroll
    for (int j = 0; j < 4; ++j) {
      int colg = bx * 128 + wn * 64 + j * 16 + lm;
      float be = b_enc[colg];
      u16* cp = Cbf + (size_t)rowg * H_ + colg;
#pragma unroll
      for (int r = 0; r < 4; ++r)
        cp[(size_t)r * H_] = f2bf(acc[i][j][r] + be);  // L2 combines per-row lines
    }
  }
}

// ---- K2: per-row histogram select from bf16 a, LDS-staged single global pass ----
__global__ __launch_bounds__(256) void k_select(const u16* __restrict__ abf,
                                                int* __restrict__ candIdx,
                                                int* __restrict__ candCnt) {
  const int row = blockIdx.x, tid = threadIdx.x;
  const u16* arow = abf + (size_t)row * H_;
  __shared__ u16 sa[H_];        // 32 KB row stage
  __shared__ int hist[NBINS];   // 8 KB
  __shared__ int coarse[256];
  __shared__ float s_cut;
  __shared__ int s_cnt;
  for (int i = tid; i < NBINS; i += 256) hist[i] = 0;
  if (tid == 0) s_cnt = 0;
  __syncthreads();
  for (int i = tid; i < H_ / 8; i += 256) {
    u16x8 v = *(const u16x8*)(arow + i * 8);
    *(u16x8*)(sa + i * 8) = v;
#pragma unroll
    for (int c = 0; c < 8; ++c) {
      float fv = bf2f(v[c]);
      int b = (int)floorf((fv + 4.0f) * 256.0f);
      b = b < 0 ? 0 : (b > NBINS - 1 ? NBINS - 1 : b);
      atomicAdd(&hist[b], 1);
    }
  }
  __syncthreads();
  {
    int s = 0;
#pragma unroll
    for (int j = 0; j < 8; ++j) s += hist[tid * 8 + j];
    coarse[tid] = s;
  }
  __syncthreads();
  if (tid == 0) {
    int c = 0, ifound = 0;
    for (int t = 255; t >= 0; --t) {
      if (c + coarse[t] >= TOPK) {
        for (int b = t * 8 + 7; b >= t * 8; --b) {
          c += hist[b];
          if (c >= TOPK) { ifound = b; break; }
        }
        break;
      }
      c += coarse[t];
    }
    // margin: bf16-GEMM error (<=0.025 proven) + bf16 storage rounding (<=0.008)
    s_cut = ((float)ifound * (1.0f / 256.0f) - 4.0f) - 0.035f;
  }
  __syncthreads();
  const float cut = s_cut;
  for (int i = tid; i < H_ / 8; i += 256) {
    u16x8 v = *(const u16x8*)(sa + i * 8);
#pragma unroll
    for (int c = 0; c < 8; ++c) {
      if (bf2f(v[c]) >= cut) {
        int p = atomicAdd(&s_cnt, 1);
        if (p < MAXC) candIdx[row * MAXC + p] = i * 8 + c;
      }
    }
  }
  __syncthreads();
  if (tid == 0) candCnt[row] = s_cnt < MAXC ? s_cnt : MAXC;
}

// ---- K3: fp64 refinement + zero-fill of f[row] (NT stores overlap gathers) ----
__global__ __launch_bounds__(256) void k_refine(const float* __restrict__ x,
                                               const float* __restrict__ b_dec,
                                               const float* __restrict__ Wenc,
                                               const float* __restrict__ b_enc,
                                               const int* __restrict__ candIdx,
                                               const int* __restrict__ candCnt,
                                               float* __restrict__ f,
                                               int* __restrict__ decIdx,
                                               float* __restrict__ decVal) {
  const int row = blockIdx.x, tid = threadIdx.x;
  const int lane = tid & 63, wave = tid >> 6;
  __shared__ double xl[F_];
  __shared__ double vals[MAXC];
  __shared__ int idxs[MAXC];
  for (int k = tid; k < F_; k += 256)
    xl[k] = (double)x[(size_t)row * F_ + k] - (double)b_dec[k];
  const int cnt = candCnt[row];
  for (int c = tid; c < cnt; c += 256) idxs[c] = candIdx[row * MAXC + c];

  // zero this row of f (abf upper-half already fully consumed by k_select)
  float* frow = f + (size_t)row * H_;
  const f32x4 z4 = {0.f, 0.f, 0.f, 0.f};
  for (int i = tid; i < H_ / 4; i += 256)
    __builtin_nontemporal_store(z4, (f32x4*)frow + i);
  __syncthreads();

  // candidate-invariant x slice -> registers (16 doubles/lane)
  double xr[16];
#pragma unroll
  for (int ch = 0; ch < 4; ++ch)
#pragma unroll
    for (int j = 0; j < 4; ++j)
      xr[ch * 4 + j] = xl[ch * 256 + lane * 4 + j];

  for (int cbase = wave * 4; cbase < cnt; cbase += 16) {
    const int n = (cnt - cbase) < 4 ? (cnt - cbase) : 4;
    int h[4];
#pragma unroll
    for (int j = 0; j < 4; ++j) h[j] = idxs[cbase + (j < n ? j : 0)];
    float4 aw[4][4];
#pragma unroll
    for (int j = 0; j < 4; ++j) {
      const float4* wj = (const float4*)(Wenc + (size_t)h[j] * F_);
#pragma unroll
      for (int ch = 0; ch < 4; ++ch) aw[j][ch] = wj[ch * 64 + lane];
    }
    double s[4] = {0.0, 0.0, 0.0, 0.0};
#pragma unroll
    for (int j = 0; j < 4; ++j)
#pragma unroll
      for (int ch = 0; ch < 4; ++ch) {
        s[j] += xr[ch * 4 + 0] * (double)aw[j][ch].x;
        s[j] += xr[ch * 4 + 1] * (double)aw[j][ch].y;
        s[j] += xr[ch * 4 + 2] * (double)aw[j][ch].z;
        s[j] += xr[ch * 4 + 3] * (double)aw[j][ch].w;
      }
#pragma unroll
    for (int off = 32; off > 0; off >>= 1) {
#pragma unroll
      for (int j = 0; j < 4; ++j) s[j] += __shfl_xor(s[j], off);
    }
    if (lane == 0) {
#pragma unroll
      for (int j = 0; j < 4; ++j)
        if (j < n) vals[cbase + j] = s[j] + (double)b_enc[h[j]];
    }
  }
  __syncthreads();

  for (int c = tid; c < cnt; c += 256) {
    const double v = vals[c];
    const int h = idxs[c];
    int rank = 0;
    for (int o = 0; o < cnt; ++o) {
      double vo = vals[o];
      rank += (vo > v) || (vo == v && idxs[o] < h);  // jax tie-break: lower idx first
    }
    if (rank < TOPK) {
      float fv = v > 0.0 ? (float)v : 0.0f;
      f[(size_t)row * H_ + h] = fv;
      decIdx[row * TOPK + rank] = h;
      decVal[row * TOPK + rank] = fv;
    }
  }
}

// ---- K4: sparse decode: xhat[b,:] = sum_j val_j * W_decT[idx_j,:] + b_dec ----
__global__ __launch_bounds__(256) void k_decode(const int* __restrict__ decIdx,
                                               const float* __restrict__ decVal,
                                               const u16* __restrict__ WdecT,
                                               const float* __restrict__ b_dec,
                                               float* __restrict__ xhat) {
  const int row = blockIdx.x, tid = threadIdx.x;
  __shared__ int sIdx[TOPK];
  __shared__ float sVal[TOPK];
  if (tid < TOPK) {
    sIdx[tid] = decIdx[row * TOPK + tid];
    sVal[tid] = decVal[row * TOPK + tid];
  }
  __syncthreads();
  const int fb = tid * 4;
  float4 bd = *(const float4*)(b_dec + fb);
  float a0 = bd.x, a1 = bd.y, a2 = bd.z, a3 = bd.w;
#pragma unroll 8
  for (int j = 0; j < TOPK; ++j) {
    const float v = sVal[j];
    const ushort4 w = *(const ushort4*)(WdecT + (size_t)sIdx[j] * F_ + fb);
    a0 += v * bf2f(w.x); a1 += v * bf2f(w.y);
    a2 += v * bf2f(w.z); a3 += v * bf2f(w.w);
  }
  float4 o; o.x = a0; o.y = a1; o.z = a2; o.w = a3;
  *(float4*)(xhat + (size_t)row * F_ + fb) = o;
}

extern "C" void kernel_launch(void* const* d_in, const int* in_sizes, int n_in,
                              void* d_out, int out_size, void* d_ws, size_t ws_size,
                              hipStream_t stream) {
  const float* x    = (const float*)d_in[0];
  const float* Wenc = (const float*)d_in[1];
  const float* benc = (const float*)d_in[2];
  const float* Wdec = (const float*)d_in[3];
  const float* bdec = (const float*)d_in[4];

  float* out  = (float*)d_out;
  float* f    = out;                       // [4096][16384] fp32
  float* xhat = out + (size_t)B_ * H_;     // [4096][1024]
  // bf16 'a' lives in the upper half of the f region (fully consumed by
  // k_select before k_refine zero-fills f) — no ws growth.
  u16* abf = (u16*)(f + (size_t)B_ * H_ / 2);  // 128 MB

  char* ws = (char*)d_ws;
  u16*  xbar    = (u16*)ws;                             // 8 MB
  u16*  wencb   = (u16*)(ws + (size_t)(8)  * 1048576);  // 32 MB
  u16*  wdecT   = (u16*)(ws + (size_t)(40) * 1048576);  // 32 MB
  int*  candIdx = (int*)(ws + (size_t)(72) * 1048576);  // 3 MB
  int*  candCnt = (int*)(ws + (size_t)(75) * 1048576);  // 16 KB
  int*  decIdx  = (int*)(ws + (size_t)(76) * 1048576);  // 1 MB
  float* decVal = (float*)(ws + (size_t)(77) * 1048576);// 1 MB

  k_xbar<<<B_ * F_ / 1024, 256, 0, stream>>>(x, bdec, xbar);
  k_cast<<<H_ * F_ / 1024, 256, 0, stream>>>(Wenc, wencb);
  k_transpose<<<dim3(H_ / 32, F_ / 32), 256, 0, stream>>>(Wdec, wdecT);
  k_gemm<<<dim3(H_ / 128, B_ / 128), 256, 0, stream>>>(xbar, wencb, benc, abf);
  k_select<<<B_, 256, 0, stream>>>(abf, candIdx, candCnt);
  k_refine<<<B_, 256, 0, stream>>>(x, bdec, Wenc, benc, candIdx, candCnt, f, decIdx, decVal);
  k_decode<<<B_, 256, 0, stream>>>(decIdx, decVal, wdecT, bdec, xhat);
}